// Round 2
// baseline (385.075 us; speedup 1.0000x reference)
//
#include <hip/hip_runtime.h>

// NonLocalBlock: B=2, C=256, N=D*H*W=6272, mid=128.
// R2b: flash-decode K-split (KS=4) to fix wave starvation (Occupancy 7%),
// with workspace footprint held under the known-good 16 MB:
//  - partial O stored as f16 in d_out (exactly out_size bytes); comb merges
//    KS partials -> f16 attnW in ws; epi converts f16->f32 while staging.
//  - attn grid (NN/32, KS, BB); each block sweeps ~24 key-tiles.
//  - K not LDS-staged: A-fragments read straight from global (each K element
//    used once per block). LDS 22272 B => 7 blocks/CU = 14 waves/CU.
//  - defer-max: skip O-rescale when __all(tmax <= m_run) (exact at THR=0).
// ws: Qg f16 | Kg f16 | VtG f16 | attnW f16 | MLg f32  = 13.25 MB.

#define BB  2
#define CC  256
#define NN  6272
#define MID 128
#define KS  4
#define NT  (NN / 64)

typedef _Float16 half4_t __attribute__((ext_vector_type(4)));
typedef _Float16 half8_t __attribute__((ext_vector_type(8)));
typedef float    floatx16 __attribute__((ext_vector_type(16)));

__device__ __forceinline__ void fma4(float4& a, const float4 v, const float s) {
    a.x += v.x * s; a.y += v.y * s; a.z += v.z * s; a.w += v.w * s;
}
__device__ __forceinline__ float dot4(const float4 a, const float4 b) {
    return a.x * b.x + a.y * b.y + a.z * b.z + a.w * b.w;
}

// ---------------------------------------------------------------------------
// Projection: e_pj[n][m] = dot(w_pj[m,:], x[b,:,n]) + bias.
// pj 0 -> Qg f16 [b][n][128]; pj 1 -> Kg f16 [b][n][128]; pj 2 -> VtG f16 [b][128][n].
// grid (NN/64, 3, BB), block 256.
// ---------------------------------------------------------------------------
__global__ __launch_bounds__(256, 2) void proj_kernel(
    const float* __restrict__ x,
    const float* __restrict__ w1, const float* __restrict__ bi1,
    const float* __restrict__ w2, const float* __restrict__ bi2,
    const float* __restrict__ w3, const float* __restrict__ bi3,
    _Float16* __restrict__ Qg, _Float16* __restrict__ Kg, _Float16* __restrict__ VtG)
{
    const int t  = threadIdx.x;
    const int n0 = blockIdx.x * 64;
    const int pj = blockIdx.y;
    const int b  = blockIdx.z;
    const float* w  = (pj == 0) ? w1 : (pj == 1) ? w2 : w3;
    const float* bi = (pj == 0) ? bi1 : (pj == 1) ? bi2 : bi3;

    __shared__ float xs[CC * 68];
    {
        const float* xb = x + (size_t)b * CC * NN;
        for (int r = t; r < CC * 16; r += 256) {
            int c = r >> 4, j = (r & 15) << 2;
            float4 v = *(const float4*)(xb + (size_t)c * NN + n0 + j);
            *(float4*)&xs[c * 68 + j] = v;
        }
    }
    __syncthreads();

    const int n4 = (t & 15) << 2;   // 4 consecutive n per thread
    const int m0 = (t >> 4) << 3;   // 8 m-rows per thread
    float4 acc4[8];
    #pragma unroll
    for (int k = 0; k < 8; ++k) acc4[k] = make_float4(0.f, 0.f, 0.f, 0.f);

    for (int cc = 0; cc < CC; cc += 4) {
        float4 xv[4];
        #pragma unroll
        for (int u = 0; u < 4; ++u)
            xv[u] = *(const float4*)&xs[(cc + u) * 68 + n4];
        #pragma unroll
        for (int k = 0; k < 8; ++k) {
            float4 wq = *(const float4*)(w + (size_t)(m0 + k) * CC + cc);
            fma4(acc4[k], xv[0], wq.x);
            fma4(acc4[k], xv[1], wq.y);
            fma4(acc4[k], xv[2], wq.z);
            fma4(acc4[k], xv[3], wq.w);
        }
    }

    const float* af = (const float*)acc4;   // af[k*4 + i], i = n-sub, k = m-sub
    float bb[8];
    #pragma unroll
    for (int k = 0; k < 8; ++k) bb[k] = bi[m0 + k];

    if (pj < 2) {
        _Float16* eo = ((pj == 0) ? Qg : Kg) + (size_t)b * NN * MID;
        #pragma unroll
        for (int i = 0; i < 4; ++i) {
            half8_t h;
            #pragma unroll
            for (int k = 0; k < 8; ++k) h[k] = (_Float16)(af[k * 4 + i] + bb[k]);
            *(half8_t*)(eo + (size_t)(n0 + n4 + i) * MID + m0) = h;
        }
    } else {
        _Float16* eo = VtG + (size_t)b * MID * NN;
        #pragma unroll
        for (int k = 0; k < 8; ++k) {
            half4_t h;
            #pragma unroll
            for (int i = 0; i < 4; ++i) h[i] = (_Float16)(af[k * 4 + i] + bb[k]);
            *(half4_t*)(eo + (size_t)(m0 + k) * NN + n0 + n4) = h;
        }
    }
}

// ---------------------------------------------------------------------------
// Flash attention partial, f16 MFMA. grid (NN/32, KS, BB), block 128 (2 waves).
// Block (q-tile, split sp) sweeps kt in [NT*sp/KS, NT*(sp+1)/KS); wave w owns
// k'-half w of each 64-key tile; independent (m,l,O); merged at the end, then
// written UNNORMALIZED as f16 to Opart[b][sp] (aliasing d_out) with (m,l) to
// MLg. K fragments are read directly from global (used once per block).
// LDS (22272 B): Vt [128][68] f16 (17408) | Pt [32][68] f16 (4352) | stats 128 f32.
// Obuf [32][132] f32 aliases Vt for the end merge.
// ---------------------------------------------------------------------------
__global__ __launch_bounds__(128, 4) void attn_kernel(
    const _Float16* __restrict__ Qg, const _Float16* __restrict__ Kg,
    const _Float16* __restrict__ VtG, _Float16* __restrict__ Opart,
    float* __restrict__ MLg)
{
    const int t    = threadIdx.x;
    const int lane = t & 63;
    const int wave = t >> 6;        // k'-half
    const int l31  = lane & 31;
    const int l5   = lane >> 5;
    const int q0   = blockIdx.x * 32;
    const int sp   = blockIdx.y;
    const int b    = blockIdx.z;
    const int kt0  = (NT * sp) / KS;
    const int kt1  = (NT * (sp + 1)) / KS;

    __shared__ __align__(16) char lds[22272];
    _Float16* Vt = (_Float16*)lds;               // 128*68 halfs
    _Float16* Pt = (_Float16*)(lds + 17408);     // 32*68 halfs
    float* stats = (float*)(lds + 21760);        // 128 f32
    float* Obuf  = (float*)lds;                  // 32*132 f32 (alias Vt)

    const _Float16* Qb = Qg + ((size_t)b * NN + q0) * MID;
    const _Float16* Kb = Kg + (size_t)b * NN * MID;
    const _Float16* Vb = VtG + (size_t)b * MID * NN;

    // Q B-frags: loop-invariant, pinned in registers.
    half8_t qf[8];
    #pragma unroll
    for (int ds = 0; ds < 8; ++ds)
        qf[ds] = *(const half8_t*)(Qb + (size_t)l31 * MID + ds * 16 + l5 * 8);

    floatx16 o[4];
    #pragma unroll
    for (int dt = 0; dt < 4; ++dt)
        #pragma unroll
        for (int j = 0; j < 16; ++j) o[dt][j] = 0.f;
    float m_run = -3.0e38f, l_run = 0.f;

    for (int kt = kt0; kt < kt1; ++kt) {
        const int nk = kt * 64;
        // ---- stage V^T tile [128][68] ----
        #pragma unroll
        for (int it = 0; it < 8; ++it) {
            int c = it * 128 + t;
            int d = c >> 3, off = (c & 7) * 8;
            *(half8_t*)(Vt + d * 68 + off) =
                *(const half8_t*)(Vb + (size_t)d * NN + nk + off);
        }
        __syncthreads();

        // ---- S^T = K . Q^T over the wave's 32-k' strip, K direct from global ----
        floatx16 s;
        #pragma unroll
        for (int j = 0; j < 16; ++j) s[j] = 0.f;
        const _Float16* krow = Kb + (size_t)(nk + wave * 32 + l31) * MID + l5 * 8;
        #pragma unroll
        for (int ds = 0; ds < 8; ++ds)
            s = __builtin_amdgcn_mfma_f32_32x32x16_f16(
                    *(const half8_t*)(krow + ds * 16), qf[ds], s, 0, 0, 0);

        // ---- online softmax (per lane: one q column, 16 of 32 k' rows) ----
        float tmax = s[0];
        #pragma unroll
        for (int j = 1; j < 16; ++j) tmax = fmaxf(tmax, s[j]);
        tmax = fmaxf(tmax, __shfl_xor(tmax, 32));

        // defer-max (THR=0): skip rescale when no lane's max grew (exact).
        if (!__all(tmax <= m_run)) {
            const float m_new = fmaxf(m_run, tmax);
            const float alpha = __expf(m_run - m_new);
            m_run = m_new;
            l_run *= alpha;
            #pragma unroll
            for (int dt = 0; dt < 4; ++dt)
                #pragma unroll
                for (int j = 0; j < 16; ++j) o[dt][j] *= alpha;
        }

        float psum = 0.f;
        _Float16* prow = Pt + l31 * 68 + wave * 32 + 4 * l5;
        #pragma unroll
        for (int g = 0; g < 4; ++g) {
            float p0 = __expf(s[4 * g + 0] - m_run);
            float p1 = __expf(s[4 * g + 1] - m_run);
            float p2 = __expf(s[4 * g + 2] - m_run);
            float p3 = __expf(s[4 * g + 3] - m_run);
            psum += (p0 + p1) + (p2 + p3);
            half4_t h;
            h[0] = (_Float16)p0; h[1] = (_Float16)p1;
            h[2] = (_Float16)p2; h[3] = (_Float16)p3;
            *(half4_t*)(prow + 8 * g) = h;   // k' = wave*32 + 8g + 4*l5 + {0..3}
        }
        psum += __shfl_xor(psum, 32);
        l_run += psum;

        // Own-wave cross-lane LDS dependency (lane l reads lane l^32's Pt
        // writes): drain lgkmcnt, no block barrier needed (quadrants disjoint).
        __builtin_amdgcn_s_waitcnt(0xC07F);

        // ---- O^T += V^T . P^T over the wave's 32-kk strip ----
        #pragma unroll
        for (int ks = 0; ks < 2; ++ks) {
            half8_t pf = *(const half8_t*)(Pt + l31 * 68 + wave * 32 + ks * 16 + l5 * 8);
            const _Float16* vcol = Vt + wave * 32 + ks * 16 + l5 * 8;
            #pragma unroll
            for (int dt = 0; dt < 4; ++dt)
                o[dt] = __builtin_amdgcn_mfma_f32_32x32x16_f16(
                            *(const half8_t*)(vcol + (dt * 32 + l31) * 68), pf,
                            o[dt], 0, 0, 0);
        }
        __syncthreads();
    }

    // ---- merge the two k'-half partials; store UNNORMALIZED f16 partial + (m,l) ----
    if (l5 == 0) {
        stats[wave * 64 + l31]      = m_run;
        stats[wave * 64 + 32 + l31] = l_run;
    }
    __syncthreads();
    const float m_o  = stats[(1 ^ wave) * 64 + l31];
    const float l_o  = stats[(1 ^ wave) * 64 + 32 + l31];
    const float m_st = fmaxf(m_run, m_o);
    const float sc   = __expf(m_run - m_st);
    const float l_st = l_run * sc + l_o * __expf(m_o - m_st);

    if (t < 32) {   // wave 0, l5 == 0, l31 == t: owns q-row q0+t
        float* mlb = MLg + ((size_t)(b * KS + sp) * 2) * NN + q0;
        mlb[t]      = m_st;
        mlb[NN + t] = l_st;
    }

    if (wave == 1) {
        #pragma unroll
        for (int dt = 0; dt < 4; ++dt)
            #pragma unroll
            for (int j = 0; j < 16; ++j) {
                int d = dt * 32 + (j & 3) + 8 * (j >> 2) + 4 * l5;
                Obuf[l31 * 132 + d] = o[dt][j] * sc;
            }
    }
    __syncthreads();
    if (wave == 0) {
        #pragma unroll
        for (int dt = 0; dt < 4; ++dt)
            #pragma unroll
            for (int j = 0; j < 16; ++j) {
                int d = dt * 32 + (j & 3) + 8 * (j >> 2) + 4 * l5;
                Obuf[l31 * 132 + d] += o[dt][j] * sc;
            }
    }
    __syncthreads();
    _Float16* Ob = Opart + ((size_t)(b * KS + sp) * NN + q0) * MID;
    #pragma unroll
    for (int it = 0; it < 4; ++it) {
        int c = it * 128 + t;           // 512 half8-chunks: 32 q-rows x 16
        int q = c >> 4, g = c & 15;
        const float* src = &Obuf[q * 132 + g * 8];
        half8_t h;
        #pragma unroll
        for (int j = 0; j < 8; ++j) h[j] = (_Float16)src[j];
        *(half8_t*)(Ob + (size_t)q * MID + g * 8) = h;
    }
}

// ---------------------------------------------------------------------------
// Combine the KS partials: attnW = sum_s O_s*exp(m_s-m) / sum_s l_s*exp(m_s-m).
// Opart f16 lives in d_out; result written as f16 to ws attnW.
// grid (NN/32, BB), block 256: thread owns (q, 16 d-cols).
// ---------------------------------------------------------------------------
__global__ __launch_bounds__(256, 4) void comb_kernel(
    const _Float16* __restrict__ Opart, const float* __restrict__ MLg,
    _Float16* __restrict__ attnW)
{
    const int t  = threadIdx.x;
    const int b  = blockIdx.y;
    const int q  = blockIdx.x * 32 + (t >> 3);
    const int dg = (t & 7) * 16;

    float mv[KS], lv[KS];
    float m_g = -3.0e38f;
    #pragma unroll
    for (int s = 0; s < KS; ++s) {
        const float* mlb = MLg + ((size_t)(b * KS + s) * 2) * NN;
        mv[s] = mlb[q];
        lv[s] = mlb[NN + q];
        m_g = fmaxf(m_g, mv[s]);
    }
    float lg = 0.f, w[KS];
    #pragma unroll
    for (int s = 0; s < KS; ++s) { w[s] = __expf(mv[s] - m_g); lg += lv[s] * w[s]; }
    const float inv = 1.0f / lg;

    float acc[16];
    #pragma unroll
    for (int j = 0; j < 16; ++j) acc[j] = 0.f;
    #pragma unroll
    for (int s = 0; s < KS; ++s) {
        const half8_t* Op = (const half8_t*)(Opart + ((size_t)(b * KS + s) * NN + q) * MID + dg);
        half8_t v0 = Op[0], v1 = Op[1];
        #pragma unroll
        for (int j = 0; j < 8; ++j) {
            acc[j]     += (float)v0[j] * w[s];
            acc[8 + j] += (float)v1[j] * w[s];
        }
    }
    half8_t h0, h1;
    #pragma unroll
    for (int j = 0; j < 8; ++j) {
        h0[j] = (_Float16)(acc[j] * inv);
        h1[j] = (_Float16)(acc[8 + j] * inv);
    }
    half8_t* Ow = (half8_t*)(attnW + ((size_t)b * NN + q) * MID + dg);
    Ow[0] = h0; Ow[1] = h1;
}

// ---------------------------------------------------------------------------
// Epilogue: out[b][c][n] = x + w4 @ attn^T + b4. grid (NN/64, BB), block 256.
// attnW is f16 [b][n][128]; converted to f32 while staging to LDS.
// ---------------------------------------------------------------------------
__global__ __launch_bounds__(256, 2) void epi_kernel(
    const _Float16* __restrict__ attnW, const float* __restrict__ w4,
    const float* __restrict__ b4, const float* __restrict__ x,
    float* __restrict__ out)
{
    const int t  = threadIdx.x;
    const int n0 = blockIdx.x * 64;
    const int b  = blockIdx.y;

    __shared__ float as[64 * 132];
    for (int r = t; r < 64 * 16; r += 256) {
        int q = r >> 4, g = r & 15;
        half8_t v = *(const half8_t*)(attnW + ((size_t)b * NN + n0 + q) * MID + g * 8);
        float* dst = &as[q * 132 + g * 8];
        #pragma unroll
        for (int j = 0; j < 8; ++j) dst[j] = (float)v[j];
    }
    __syncthreads();

    const int n4 = (t & 15) << 2;
    const int c0 = (t >> 4) << 4;
    float4 accE[16];
    #pragma unroll
    for (int k = 0; k < 16; ++k) accE[k] = make_float4(0.f, 0.f, 0.f, 0.f);

    for (int ms = 0; ms < 32; ++ms) {
        float4 av[4];
        #pragma unroll
        for (int i = 0; i < 4; ++i)
            av[i] = *(const float4*)&as[(n4 + i) * 132 + (ms << 2)];
        #pragma unroll
        for (int k = 0; k < 16; ++k) {
            float4 wq = *(const float4*)(w4 + (size_t)(c0 + k) * MID + (ms << 2));
            accE[k].x += dot4(av[0], wq);
            accE[k].y += dot4(av[1], wq);
            accE[k].z += dot4(av[2], wq);
            accE[k].w += dot4(av[3], wq);
        }
    }

    #pragma unroll
    for (int k = 0; k < 16; ++k) {
        const int c = c0 + k;
        const float bv = b4[c];
        const size_t off = ((size_t)b * CC + c) * NN + n0 + n4;
        float4 xr = *(const float4*)(x + off);
        float4 r;
        r.x = accE[k].x + bv + xr.x;
        r.y = accE[k].y + bv + xr.y;
        r.z = accE[k].z + bv + xr.z;
        r.w = accE[k].w + bv + xr.w;
        *(float4*)(out + off) = r;
    }
}

extern "C" void kernel_launch(void* const* d_in, const int* in_sizes, int n_in,
                              void* d_out, int out_size, void* d_ws, size_t ws_size,
                              hipStream_t stream)
{
    const float* x  = (const float*)d_in[0];
    const float* w1 = (const float*)d_in[1];
    const float* b1 = (const float*)d_in[2];
    const float* w2 = (const float*)d_in[3];
    const float* b2 = (const float*)d_in[4];
    const float* w3 = (const float*)d_in[5];
    const float* b3 = (const float*)d_in[6];
    const float* w4 = (const float*)d_in[7];
    const float* b4 = (const float*)d_in[8];
    float* out = (float*)d_out;

    // ws: Qg f16 [B][N][128] | Kg f16 [B][N][128] | VtG f16 [B][128][N]
    //   | attnW f16 [B][N][128] | MLg f32 [B][KS][2][N]   (13.25 MB total)
    // Opart f16 [B][KS][N][128] aliases d_out (exactly out_size bytes).
    _Float16* Qg    = (_Float16*)d_ws;
    _Float16* Kg    = Qg + (size_t)BB * NN * MID;
    _Float16* VtG   = Kg + (size_t)BB * NN * MID;
    _Float16* attnW = VtG + (size_t)BB * NN * MID;
    float* MLg      = (float*)(attnW + (size_t)BB * NN * MID);
    _Float16* Opart = (_Float16*)d_out;

    proj_kernel<<<dim3(NN / 64, 3, BB), 256, 0, stream>>>(x, w1, b1, w2, b2, w3, b3, Qg, Kg, VtG);
    attn_kernel<<<dim3(NN / 32, KS, BB), 128, 0, stream>>>(Qg, Kg, VtG, Opart, MLg);
    comb_kernel<<<dim3(NN / 32, BB), 256, 0, stream>>>(Opart, MLg, attnW);
    epi_kernel<<<dim3(NN / 64, BB), 256, 0, stream>>>(attnW, w4, b4, x, out);
}

// Round 3
// 369.273 us; speedup vs baseline: 1.0428x; 1.0428x over previous
//
#include <hip/hip_runtime.h>

// NonLocalBlock: B=2, C=256, N=D*H*W=6272, mid=128.
// R3: flash-decode K-split KS=2 with the PROVEN R0 inner loop restored:
//  - K tile staged in LDS (coalesced half8 loads), MFMA A-operand reads LDS.
//    (R2b's K-direct-from-global put global latency in the MFMA chain and
//    thrashed L2: FETCH 26.7->110 MB, attn 167->232 us. Reverted.)
//  - grid (NN/32, KS=2, BB) = 784 blocks; LDS 39680 B -> 4 blocks/CU cap,
//    3.06 blocks/CU resident, single occupancy round (2x R0's residency).
//  - partial O stored f16 in d_out; comb merges -> f16 attnW; epi converts.
//  - defer-max: skip O-rescale when __all(tmax <= m_run) (exact at THR=0).
// ws: Qg f16 | Kg f16 | VtG f16 | attnW f16 | MLg f32  ~= 13.0 MB.

#define BB  2
#define CC  256
#define NN  6272
#define MID 128
#define KS  2
#define NT  (NN / 64)

typedef _Float16 half4_t __attribute__((ext_vector_type(4)));
typedef _Float16 half8_t __attribute__((ext_vector_type(8)));
typedef float    floatx16 __attribute__((ext_vector_type(16)));

__device__ __forceinline__ void fma4(float4& a, const float4 v, const float s) {
    a.x += v.x * s; a.y += v.y * s; a.z += v.z * s; a.w += v.w * s;
}
__device__ __forceinline__ float dot4(const float4 a, const float4 b) {
    return a.x * b.x + a.y * b.y + a.z * b.z + a.w * b.w;
}

// ---------------------------------------------------------------------------
// Projection: e_pj[n][m] = dot(w_pj[m,:], x[b,:,n]) + bias.
// pj 0 -> Qg f16 [b][n][128]; pj 1 -> Kg f16 [b][n][128]; pj 2 -> VtG f16 [b][128][n].
// grid (NN/64, 3, BB), block 256.
// ---------------------------------------------------------------------------
__global__ __launch_bounds__(256, 2) void proj_kernel(
    const float* __restrict__ x,
    const float* __restrict__ w1, const float* __restrict__ bi1,
    const float* __restrict__ w2, const float* __restrict__ bi2,
    const float* __restrict__ w3, const float* __restrict__ bi3,
    _Float16* __restrict__ Qg, _Float16* __restrict__ Kg, _Float16* __restrict__ VtG)
{
    const int t  = threadIdx.x;
    const int n0 = blockIdx.x * 64;
    const int pj = blockIdx.y;
    const int b  = blockIdx.z;
    const float* w  = (pj == 0) ? w1 : (pj == 1) ? w2 : w3;
    const float* bi = (pj == 0) ? bi1 : (pj == 1) ? bi2 : bi3;

    __shared__ float xs[CC * 68];
    {
        const float* xb = x + (size_t)b * CC * NN;
        for (int r = t; r < CC * 16; r += 256) {
            int c = r >> 4, j = (r & 15) << 2;
            float4 v = *(const float4*)(xb + (size_t)c * NN + n0 + j);
            *(float4*)&xs[c * 68 + j] = v;
        }
    }
    __syncthreads();

    const int n4 = (t & 15) << 2;   // 4 consecutive n per thread
    const int m0 = (t >> 4) << 3;   // 8 m-rows per thread
    float4 acc4[8];
    #pragma unroll
    for (int k = 0; k < 8; ++k) acc4[k] = make_float4(0.f, 0.f, 0.f, 0.f);

    for (int cc = 0; cc < CC; cc += 4) {
        float4 xv[4];
        #pragma unroll
        for (int u = 0; u < 4; ++u)
            xv[u] = *(const float4*)&xs[(cc + u) * 68 + n4];
        #pragma unroll
        for (int k = 0; k < 8; ++k) {
            float4 wq = *(const float4*)(w + (size_t)(m0 + k) * CC + cc);
            fma4(acc4[k], xv[0], wq.x);
            fma4(acc4[k], xv[1], wq.y);
            fma4(acc4[k], xv[2], wq.z);
            fma4(acc4[k], xv[3], wq.w);
        }
    }

    const float* af = (const float*)acc4;   // af[k*4 + i], i = n-sub, k = m-sub
    float bb[8];
    #pragma unroll
    for (int k = 0; k < 8; ++k) bb[k] = bi[m0 + k];

    if (pj < 2) {
        _Float16* eo = ((pj == 0) ? Qg : Kg) + (size_t)b * NN * MID;
        #pragma unroll
        for (int i = 0; i < 4; ++i) {
            half8_t h;
            #pragma unroll
            for (int k = 0; k < 8; ++k) h[k] = (_Float16)(af[k * 4 + i] + bb[k]);
            *(half8_t*)(eo + (size_t)(n0 + n4 + i) * MID + m0) = h;
        }
    } else {
        _Float16* eo = VtG + (size_t)b * MID * NN;
        #pragma unroll
        for (int k = 0; k < 8; ++k) {
            half4_t h;
            #pragma unroll
            for (int i = 0; i < 4; ++i) h[i] = (_Float16)(af[k * 4 + i] + bb[k]);
            *(half4_t*)(eo + (size_t)(m0 + k) * NN + n0 + n4) = h;
        }
    }
}

// ---------------------------------------------------------------------------
// Flash attention partial, f16 MFMA. grid (NN/32, KS, BB), block 128 (2 waves).
// Block (q-tile, split sp) sweeps kt in [NT*sp/KS, NT*(sp+1)/KS); wave w owns
// k'-half w of each 64-key tile; independent (m,l,O); merged at the end, then
// written UNNORMALIZED as f16 to Opart[b][sp] (aliasing d_out) with (m,l) to MLg.
// S^T tile: D[k'][q]: col q = lane&31, row k' = (reg&3)+8*(reg>>2)+4*(lane>>5).
// LDS (39680 B):
//   Ks  [64][136] f16  (17408 B)   A-operand of S^T = K.Q^T
//   Vt  [128][68] f16  (17408 B)   A-operand of O^T = V^T.P^T
//   Pt  [32][68]  f16  ( 4352 B)   B-operand (P^T), written from S^T regs
//   stats 128 f32      (  512 B)
//   Obuf [32][132] f32 aliases Ks for the end merge.
// ---------------------------------------------------------------------------
__global__ __launch_bounds__(128, 4) void attn_kernel(
    const _Float16* __restrict__ Qg, const _Float16* __restrict__ Kg,
    const _Float16* __restrict__ VtG, _Float16* __restrict__ Opart,
    float* __restrict__ MLg)
{
    const int t    = threadIdx.x;
    const int lane = t & 63;
    const int wave = t >> 6;        // k'-half
    const int l31  = lane & 31;
    const int l5   = lane >> 5;
    const int q0   = blockIdx.x * 32;
    const int sp   = blockIdx.y;
    const int b    = blockIdx.z;
    const int kt0  = (NT * sp) / KS;
    const int kt1  = (NT * (sp + 1)) / KS;

    __shared__ __align__(16) char lds[39680];
    _Float16* Ks = (_Float16*)lds;                       // 64*136 halfs
    _Float16* Vt = (_Float16*)(lds + 17408);             // 128*68 halfs
    _Float16* Pt = (_Float16*)(lds + 34816);             // 32*68 halfs
    float* stats = (float*)(lds + 39168);                // 128 f32
    float* Obuf  = (float*)lds;                          // 32*132 f32 (alias Ks)

    const _Float16* Qb = Qg + ((size_t)b * NN + q0) * MID;
    const _Float16* Kb = Kg + (size_t)b * NN * MID;
    const _Float16* Vb = VtG + (size_t)b * MID * NN;

    // Q B-frags: loop-invariant, pinned in registers.
    half8_t qf[8];
    #pragma unroll
    for (int ds = 0; ds < 8; ++ds)
        qf[ds] = *(const half8_t*)(Qb + (size_t)l31 * MID + ds * 16 + l5 * 8);

    floatx16 o[4];
    #pragma unroll
    for (int dt = 0; dt < 4; ++dt)
        #pragma unroll
        for (int j = 0; j < 16; ++j) o[dt][j] = 0.f;
    float m_run = -3.0e38f, l_run = 0.f;

    for (int kt = kt0; kt < kt1; ++kt) {
        const int nk = kt * 64;
        // ---- stage K tile [64][136] and V^T tile [128][68] ----
        #pragma unroll
        for (int it = 0; it < 8; ++it) {
            int c = it * 128 + t;
            int r = c >> 4, off = (c & 15) * 8;
            *(half8_t*)(Ks + r * 136 + off) =
                *(const half8_t*)(Kb + (size_t)(nk + r) * MID + off);
        }
        #pragma unroll
        for (int it = 0; it < 8; ++it) {
            int c = it * 128 + t;
            int d = c >> 3, off = (c & 7) * 8;
            *(half8_t*)(Vt + d * 68 + off) =
                *(const half8_t*)(Vb + (size_t)d * NN + nk + off);
        }
        __syncthreads();

        // ---- S^T = K . Q^T over the wave's 32-k' strip ----
        floatx16 s;
        #pragma unroll
        for (int j = 0; j < 16; ++j) s[j] = 0.f;
        const _Float16* krow = Ks + (wave * 32 + l31) * 136 + l5 * 8;
        #pragma unroll
        for (int ds = 0; ds < 8; ++ds)
            s = __builtin_amdgcn_mfma_f32_32x32x16_f16(
                    *(const half8_t*)(krow + ds * 16), qf[ds], s, 0, 0, 0);

        // ---- online softmax (per lane: one q column, 16 of 32 k' rows) ----
        float tmax = s[0];
        #pragma unroll
        for (int j = 1; j < 16; ++j) tmax = fmaxf(tmax, s[j]);
        tmax = fmaxf(tmax, __shfl_xor(tmax, 32));

        // defer-max (THR=0): skip rescale when no lane's max grew (exact).
        if (!__all(tmax <= m_run)) {
            const float m_new = fmaxf(m_run, tmax);
            const float alpha = __expf(m_run - m_new);
            m_run = m_new;
            l_run *= alpha;
            #pragma unroll
            for (int dt = 0; dt < 4; ++dt)
                #pragma unroll
                for (int j = 0; j < 16; ++j) o[dt][j] *= alpha;
        }

        float psum = 0.f;
        _Float16* prow = Pt + l31 * 68 + wave * 32 + 4 * l5;
        #pragma unroll
        for (int g = 0; g < 4; ++g) {
            float p0 = __expf(s[4 * g + 0] - m_run);
            float p1 = __expf(s[4 * g + 1] - m_run);
            float p2 = __expf(s[4 * g + 2] - m_run);
            float p3 = __expf(s[4 * g + 3] - m_run);
            psum += (p0 + p1) + (p2 + p3);
            half4_t h;
            h[0] = (_Float16)p0; h[1] = (_Float16)p1;
            h[2] = (_Float16)p2; h[3] = (_Float16)p3;
            *(half4_t*)(prow + 8 * g) = h;   // k' = wave*32 + 8g + 4*l5 + {0..3}
        }
        psum += __shfl_xor(psum, 32);
        l_run += psum;

        // Own-wave cross-lane LDS dependency (lane l reads lane l^32's Pt
        // writes): drain lgkmcnt, no block barrier needed (quadrants disjoint).
        __builtin_amdgcn_s_waitcnt(0xC07F);

        // ---- O^T += V^T . P^T over the wave's 32-kk strip ----
        #pragma unroll
        for (int ks = 0; ks < 2; ++ks) {
            half8_t pf = *(const half8_t*)(Pt + l31 * 68 + wave * 32 + ks * 16 + l5 * 8);
            const _Float16* vcol = Vt + wave * 32 + ks * 16 + l5 * 8;
            #pragma unroll
            for (int dt = 0; dt < 4; ++dt)
                o[dt] = __builtin_amdgcn_mfma_f32_32x32x16_f16(
                            *(const half8_t*)(vcol + (dt * 32 + l31) * 68), pf,
                            o[dt], 0, 0, 0);
        }
        __syncthreads();
    }

    // ---- merge the two k'-half partials; store UNNORMALIZED f16 partial + (m,l) ----
    if (l5 == 0) {
        stats[wave * 64 + l31]      = m_run;
        stats[wave * 64 + 32 + l31] = l_run;
    }
    __syncthreads();
    const float m_o  = stats[(1 ^ wave) * 64 + l31];
    const float l_o  = stats[(1 ^ wave) * 64 + 32 + l31];
    const float m_st = fmaxf(m_run, m_o);
    const float sc   = __expf(m_run - m_st);
    const float l_st = l_run * sc + l_o * __expf(m_o - m_st);

    if (t < 32) {   // wave 0, l5 == 0, l31 == t: owns q-row q0+t
        float* mlb = MLg + ((size_t)(b * KS + sp) * 2) * NN + q0;
        mlb[t]      = m_st;
        mlb[NN + t] = l_st;
    }

    if (wave == 1) {
        #pragma unroll
        for (int dt = 0; dt < 4; ++dt)
            #pragma unroll
            for (int j = 0; j < 16; ++j) {
                int d = dt * 32 + (j & 3) + 8 * (j >> 2) + 4 * l5;
                Obuf[l31 * 132 + d] = o[dt][j] * sc;
            }
    }
    __syncthreads();
    if (wave == 0) {
        #pragma unroll
        for (int dt = 0; dt < 4; ++dt)
            #pragma unroll
            for (int j = 0; j < 16; ++j) {
                int d = dt * 32 + (j & 3) + 8 * (j >> 2) + 4 * l5;
                Obuf[l31 * 132 + d] += o[dt][j] * sc;
            }
    }
    __syncthreads();
    _Float16* Ob = Opart + ((size_t)(b * KS + sp) * NN + q0) * MID;
    #pragma unroll
    for (int it = 0; it < 4; ++it) {
        int c = it * 128 + t;           // 512 half8-chunks: 32 q-rows x 16
        int q = c >> 4, g = c & 15;
        const float* src = &Obuf[q * 132 + g * 8];
        half8_t h;
        #pragma unroll
        for (int j = 0; j < 8; ++j) h[j] = (_Float16)src[j];
        *(half8_t*)(Ob + (size_t)q * MID + g * 8) = h;
    }
}

// ---------------------------------------------------------------------------
// Combine the KS partials: attnW = sum_s O_s*exp(m_s-m) / sum_s l_s*exp(m_s-m).
// Opart f16 lives in d_out; result written as f16 to ws attnW.
// grid (NN/32, BB), block 256: thread owns (q, 16 d-cols).
// ---------------------------------------------------------------------------
__global__ __launch_bounds__(256, 4) void comb_kernel(
    const _Float16* __restrict__ Opart, const float* __restrict__ MLg,
    _Float16* __restrict__ attnW)
{
    const int t  = threadIdx.x;
    const int b  = blockIdx.y;
    const int q  = blockIdx.x * 32 + (t >> 3);
    const int dg = (t & 7) * 16;

    float mv[KS], lv[KS];
    float m_g = -3.0e38f;
    #pragma unroll
    for (int s = 0; s < KS; ++s) {
        const float* mlb = MLg + ((size_t)(b * KS + s) * 2) * NN;
        mv[s] = mlb[q];
        lv[s] = mlb[NN + q];
        m_g = fmaxf(m_g, mv[s]);
    }
    float lg = 0.f, w[KS];
    #pragma unroll
    for (int s = 0; s < KS; ++s) { w[s] = __expf(mv[s] - m_g); lg += lv[s] * w[s]; }
    const float inv = 1.0f / lg;

    float acc[16];
    #pragma unroll
    for (int j = 0; j < 16; ++j) acc[j] = 0.f;
    #pragma unroll
    for (int s = 0; s < KS; ++s) {
        const half8_t* Op = (const half8_t*)(Opart + ((size_t)(b * KS + s) * NN + q) * MID + dg);
        half8_t v0 = Op[0], v1 = Op[1];
        #pragma unroll
        for (int j = 0; j < 8; ++j) {
            acc[j]     += (float)v0[j] * w[s];
            acc[8 + j] += (float)v1[j] * w[s];
        }
    }
    half8_t h0, h1;
    #pragma unroll
    for (int j = 0; j < 8; ++j) {
        h0[j] = (_Float16)(acc[j] * inv);
        h1[j] = (_Float16)(acc[8 + j] * inv);
    }
    half8_t* Ow = (half8_t*)(attnW + ((size_t)b * NN + q) * MID + dg);
    Ow[0] = h0; Ow[1] = h1;
}

// ---------------------------------------------------------------------------
// Epilogue: out[b][c][n] = x + w4 @ attn^T + b4. grid (NN/64, BB), block 256.
// attnW is f16 [b][n][128]; converted to f32 while staging to LDS.
// ---------------------------------------------------------------------------
__global__ __launch_bounds__(256, 2) void epi_kernel(
    const _Float16* __restrict__ attnW, const float* __restrict__ w4,
    const float* __restrict__ b4, const float* __restrict__ x,
    float* __restrict__ out)
{
    const int t  = threadIdx.x;
    const int n0 = blockIdx.x * 64;
    const int b  = blockIdx.y;

    __shared__ float as[64 * 132];
    for (int r = t; r < 64 * 16; r += 256) {
        int q = r >> 4, g = r & 15;
        half8_t v = *(const half8_t*)(attnW + ((size_t)b * NN + n0 + q) * MID + g * 8);
        float* dst = &as[q * 132 + g * 8];
        #pragma unroll
        for (int j = 0; j < 8; ++j) dst[j] = (float)v[j];
    }
    __syncthreads();

    const int n4 = (t & 15) << 2;
    const int c0 = (t >> 4) << 4;
    float4 accE[16];
    #pragma unroll
    for (int k = 0; k < 16; ++k) accE[k] = make_float4(0.f, 0.f, 0.f, 0.f);

    for (int ms = 0; ms < 32; ++ms) {
        float4 av[4];
        #pragma unroll
        for (int i = 0; i < 4; ++i)
            av[i] = *(const float4*)&as[(n4 + i) * 132 + (ms << 2)];
        #pragma unroll
        for (int k = 0; k < 16; ++k) {
            float4 wq = *(const float4*)(w4 + (size_t)(c0 + k) * MID + (ms << 2));
            accE[k].x += dot4(av[0], wq);
            accE[k].y += dot4(av[1], wq);
            accE[k].z += dot4(av[2], wq);
            accE[k].w += dot4(av[3], wq);
        }
    }

    #pragma unroll
    for (int k = 0; k < 16; ++k) {
        const int c = c0 + k;
        const float bv = b4[c];
        const size_t off = ((size_t)b * CC + c) * NN + n0 + n4;
        float4 xr = *(const float4*)(x + off);
        float4 r;
        r.x = accE[k].x + bv + xr.x;
        r.y = accE[k].y + bv + xr.y;
        r.z = accE[k].z + bv + xr.z;
        r.w = accE[k].w + bv + xr.w;
        *(float4*)(out + off) = r;
    }
}

extern "C" void kernel_launch(void* const* d_in, const int* in_sizes, int n_in,
                              void* d_out, int out_size, void* d_ws, size_t ws_size,
                              hipStream_t stream)
{
    const float* x  = (const float*)d_in[0];
    const float* w1 = (const float*)d_in[1];
    const float* b1 = (const float*)d_in[2];
    const float* w2 = (const float*)d_in[3];
    const float* b2 = (const float*)d_in[4];
    const float* w3 = (const float*)d_in[5];
    const float* b3 = (const float*)d_in[6];
    const float* w4 = (const float*)d_in[7];
    const float* b4 = (const float*)d_in[8];
    float* out = (float*)d_out;

    // ws: Qg f16 [B][N][128] | Kg f16 [B][N][128] | VtG f16 [B][128][N]
    //   | attnW f16 [B][N][128] | MLg f32 [B][KS][2][N]   (~13.0 MB total)
    // Opart f16 [B][KS][N][128] aliases d_out (KS=2: 6.4 MB <= out_size).
    _Float16* Qg    = (_Float16*)d_ws;
    _Float16* Kg    = Qg + (size_t)BB * NN * MID;
    _Float16* VtG   = Kg + (size_t)BB * NN * MID;
    _Float16* attnW = VtG + (size_t)BB * NN * MID;
    float* MLg      = (float*)(attnW + (size_t)BB * NN * MID);
    _Float16* Opart = (_Float16*)d_out;

    proj_kernel<<<dim3(NN / 64, 3, BB), 256, 0, stream>>>(x, w1, b1, w2, b2, w3, b3, Qg, Kg, VtG);
    attn_kernel<<<dim3(NN / 32, KS, BB), 128, 0, stream>>>(Qg, Kg, VtG, Opart, MLg);
    comb_kernel<<<dim3(NN / 32, BB), 256, 0, stream>>>(Opart, MLg, attnW);
    epi_kernel<<<dim3(NN / 64, BB), 256, 0, stream>>>(attnW, w4, b4, x, out);
}